// Round 1
// baseline (85.781 us; speedup 1.0000x reference)
//
#include <hip/hip_runtime.h>
#include <hip/hip_bf16.h>
#include <stdint.h>

// Problem: B=4096 rows, F=512 formulas, D=512 dims.
// dist2[b,f] = sum_d s2[f,d]*x2[b,d] - 2*sum_d s2*mu*x + c[f]
//  => GEMM M=4096 N=512 K=1024 over bf16 operands A=[x2|x], W=[s2|-2*s2*mu].
#define BB 4096
#define FF 512
#define DD 512
#define KDIM 1024

typedef __bf16 bf16x8 __attribute__((ext_vector_type(8)));
typedef float f32x4 __attribute__((ext_vector_type(4)));

__device__ __forceinline__ unsigned short f2bf(float f) {
  unsigned u = __builtin_bit_cast(unsigned, f);
  u += 0x7FFFu + ((u >> 16) & 1u);   // RNE
  return (unsigned short)(u >> 16);
}

__device__ __forceinline__ void async16(const void* g, void* l) {
  auto gp = reinterpret_cast<const __attribute__((address_space(1))) uint32_t*>(
      reinterpret_cast<uintptr_t>(g));
  auto lp = reinterpret_cast<__attribute__((address_space(3))) uint32_t*>(
      reinterpret_cast<uintptr_t>(l));
  __builtin_amdgcn_global_load_lds(gp, lp, 16, 0, 0);
}

// ---------------- prep: blocks [0,512) build W + c; blocks [512,2560) build A
__global__ __launch_bounds__(256) void prep_kernel(
    const float* __restrict__ x, const float* __restrict__ mu,
    const float* __restrict__ sg, unsigned short* __restrict__ A,
    unsigned short* __restrict__ W, float* __restrict__ c) {
  __shared__ float red[4];
  const int bid = blockIdx.x;
  const int t = threadIdx.x;
  if (bid < FF) {
    const int f = bid;
    float part = 0.f;
#pragma unroll
    for (int dd = 0; dd < 2; ++dd) {
      const int d = t + dd * 256;
      const float m = mu[f * DD + d];
      const float s = sg[f * DD + d];
      const float s2 = s * s;
      W[f * KDIM + d] = f2bf(s2);
      W[f * KDIM + DD + d] = f2bf(-2.f * s2 * m);
      part += s2 * m * m;
    }
#pragma unroll
    for (int off = 32; off > 0; off >>= 1) part += __shfl_down(part, off, 64);
    const int lane = t & 63, wave = t >> 6;
    if (lane == 0) red[wave] = part;
    __syncthreads();
    if (t == 0) c[f] = red[0] + red[1] + red[2] + red[3];
  } else {
    const int gid = (bid - FF) * 256 + t;     // 2048 blocks cover B*D/4
    const int i4 = gid * 4;
    const float4 v = *(const float4*)(x + i4);
    const int b = i4 >> 9;
    const int d = i4 & 511;
    ushort4 q2, q1;
    q2.x = f2bf(v.x * v.x); q2.y = f2bf(v.y * v.y);
    q2.z = f2bf(v.z * v.z); q2.w = f2bf(v.w * v.w);
    q1.x = f2bf(v.x); q1.y = f2bf(v.y); q1.z = f2bf(v.z); q1.w = f2bf(v.w);
    *(ushort4*)(A + (size_t)b * KDIM + d) = q2;
    *(ushort4*)(A + (size_t)b * KDIM + DD + d) = q1;
  }
}

// ---------------- GEMM 64x64 tile, BK=64, 4 waves, fused loc epilogue
// LDS column-XOR swizzle: 16B chunk at logical c16 of row r lives at phys
// c16 ^ (r&7). Staging picks global addresses accordingly (global_load_lds
// LDS side is forced to base + lane*16).
__global__ __launch_bounds__(256) void gemm_kernel(
    const unsigned short* __restrict__ A, const unsigned short* __restrict__ W,
    const float* __restrict__ c, float* __restrict__ out) {
  __shared__ __align__(16) unsigned short As[64 * 64];
  __shared__ __align__(16) unsigned short Bs[64 * 64];
  const int m0 = blockIdx.y * 64;
  const int n0 = blockIdx.x * 64;
  const int tid = threadIdx.x;
  const int lane = tid & 63;
  const int wave = tid >> 6;

  f32x4 acc[2][2];
#pragma unroll
  for (int i = 0; i < 2; ++i)
#pragma unroll
    for (int j = 0; j < 2; ++j) acc[i][j] = (f32x4){0.f, 0.f, 0.f, 0.f};

  const int srow = lane >> 3;          // 0..7 within 8-row group
  const int sc16 = lane & 7;           // phys 16B chunk
  const int gcol = (sc16 ^ srow) * 8;  // swizzled logical column (elements)
  const int quad = lane >> 4;
  const int r = lane & 15;
  const int wm = (wave & 1) * 32;
  const int wn = (wave >> 1) * 32;

  for (int kt = 0; kt < KDIM / 64; ++kt) {
    const int k0 = kt * 64;
    __syncthreads();
#pragma unroll
    for (int tI = 0; tI < 2; ++tI) {
      const int rbase = wave * 16 + tI * 8;
      async16(A + (size_t)(m0 + rbase + srow) * KDIM + k0 + gcol, &As[rbase * 64]);
      async16(W + (size_t)(n0 + rbase + srow) * KDIM + k0 + gcol, &Bs[rbase * 64]);
    }
    __syncthreads();  // drains vmcnt before s_barrier
#pragma unroll
    for (int kk = 0; kk < 2; ++kk) {
      const int lc = kk * 4 + quad;  // logical 16B chunk
      const int pc = (lc ^ (r & 7)) * 8;
      bf16x8 a0 = *(const bf16x8*)&As[(wm + r) * 64 + pc];
      bf16x8 a1 = *(const bf16x8*)&As[(wm + 16 + r) * 64 + pc];
      bf16x8 b0 = *(const bf16x8*)&Bs[(wn + r) * 64 + pc];
      bf16x8 b1 = *(const bf16x8*)&Bs[(wn + 16 + r) * 64 + pc];
      acc[0][0] = __builtin_amdgcn_mfma_f32_16x16x32_bf16(a0, b0, acc[0][0], 0, 0, 0);
      acc[0][1] = __builtin_amdgcn_mfma_f32_16x16x32_bf16(a0, b1, acc[0][1], 0, 0, 0);
      acc[1][0] = __builtin_amdgcn_mfma_f32_16x16x32_bf16(a1, b0, acc[1][0], 0, 0, 0);
      acc[1][1] = __builtin_amdgcn_mfma_f32_16x16x32_bf16(a1, b1, acc[1][1], 0, 0, 0);
    }
  }

  // epilogue: D layout col=lane&15, row=(lane>>4)*4+reg
  const int col = lane & 15;
#pragma unroll
  for (int j = 0; j < 2; ++j) {
    const int f = n0 + wn + j * 16 + col;
    const float cf = c[f];
#pragma unroll
    for (int i = 0; i < 2; ++i) {
      const int mbase = m0 + wm + i * 16 + quad * 4;
#pragma unroll
      for (int rr = 0; rr < 4; ++rr) {
        const float d2 = acc[i][j][rr] + cf;
        const float loc = __expf(-sqrtf(fmaxf(d2, 0.f)));
        out[(size_t)(mbase + rr) * FF + f] = loc;
      }
    }
  }
}

// ---------------- softmax: 4 rows/block, one wave per row, in-place
__global__ __launch_bounds__(256) void softmax_kernel(
    float* __restrict__ out, const float* __restrict__ temp) {
  const int lane = threadIdx.x & 63;
  const int wave = threadIdx.x >> 6;
  const int row = blockIdx.x * 4 + wave;
  const float s = 1.f / (1.f + __expf(-temp[0]));
  float4* p = (float4*)(out + (size_t)row * FF + lane * 8);
  const float4 v0 = p[0];
  const float4 v1 = p[1];
  float l[8] = {v0.x * s, v0.y * s, v0.z * s, v0.w * s,
                v1.x * s, v1.y * s, v1.z * s, v1.w * s};
  float mx = l[0];
#pragma unroll
  for (int i = 1; i < 8; ++i) mx = fmaxf(mx, l[i]);
#pragma unroll
  for (int off = 32; off > 0; off >>= 1) mx = fmaxf(mx, __shfl_xor(mx, off, 64));
  float e[8], sum = 0.f;
#pragma unroll
  for (int i = 0; i < 8; ++i) { e[i] = __expf(l[i] - mx); sum += e[i]; }
#pragma unroll
  for (int off = 32; off > 0; off >>= 1) sum += __shfl_xor(sum, off, 64);
  const float inv = 1.f / sum;
  float4 w0 = {e[0] * inv, e[1] * inv, e[2] * inv, e[3] * inv};
  float4 w1 = {e[4] * inv, e[5] * inv, e[6] * inv, e[7] * inv};
  p[0] = w0; p[1] = w1;
}

// ---------------- fallback (no workspace): fp32 direct
__global__ __launch_bounds__(256) void naive_loc(
    const float* __restrict__ x, const float* __restrict__ mu,
    const float* __restrict__ sg, float* __restrict__ out) {
  __shared__ float xs[DD];
  const int b = blockIdx.x;
  for (int d = threadIdx.x; d < DD; d += 256) xs[d] = x[(size_t)b * DD + d];
  __syncthreads();
  for (int f = threadIdx.x; f < FF; f += 256) {
    float acc = 0.f;
    for (int d = 0; d < DD; ++d) {
      const float s = sg[(size_t)f * DD + d];
      const float df = (xs[d] - mu[(size_t)f * DD + d]) * s;
      acc = fmaf(df, df, acc);
    }
    out[(size_t)b * FF + f] = __expf(-sqrtf(acc));
  }
}

extern "C" void kernel_launch(void* const* d_in, const int* in_sizes, int n_in,
                              void* d_out, int out_size, void* d_ws, size_t ws_size,
                              hipStream_t stream) {
  const float* x = (const float*)d_in[0];
  const float* mu = (const float*)d_in[1];
  const float* sg = (const float*)d_in[2];
  const float* temp = (const float*)d_in[3];
  float* out = (float*)d_out;

  const size_t needA = (size_t)BB * KDIM * 2;          // 8 MB
  const size_t needW = (size_t)FF * KDIM * 2;          // 1 MB
  const size_t needC = (size_t)FF * 4;                 // 2 KB
  if (ws_size >= needA + needW + needC) {
    unsigned short* A = (unsigned short*)d_ws;
    unsigned short* W = A + (size_t)BB * KDIM;
    float* c = (float*)(W + (size_t)FF * KDIM);
    prep_kernel<<<FF + (BB * DD / 4) / 256, 256, 0, stream>>>(x, mu, sg, A, W, c);
    gemm_kernel<<<dim3(FF / 64, BB / 64), 256, 0, stream>>>(A, W, c, out);
  } else {
    naive_loc<<<BB, 256, 0, stream>>>(x, mu, sg, out);
  }
  softmax_kernel<<<BB / 4, 256, 0, stream>>>(out, temp);
}

// Round 2
// 85.286 us; speedup vs baseline: 1.0058x; 1.0058x over previous
//
#include <hip/hip_runtime.h>
#include <hip/hip_bf16.h>
#include <stdint.h>

// dist2[b,f] = sum_d s2[f,d]*x2[b,d] - 2*sum_d s2*mu*x + c[f]
//  => GEMM M=4096 N=512 K=1024, bf16 operands A=[x2|x], W=[s2|-2*s2*mu].
#define BB 4096
#define FF 512
#define DD 512
#define KDIM 1024

typedef __bf16 bf16x8 __attribute__((ext_vector_type(8)));
typedef float f32x4 __attribute__((ext_vector_type(4)));
typedef unsigned short u16x8 __attribute__((ext_vector_type(8)));

__device__ __forceinline__ unsigned short f2bf(float f) {
  unsigned u = __builtin_bit_cast(unsigned, f);
  u += 0x7FFFu + ((u >> 16) & 1u);   // RNE
  return (unsigned short)(u >> 16);
}

__device__ __forceinline__ void async16(const void* g, void* l) {
  auto gp = reinterpret_cast<const __attribute__((address_space(1))) uint32_t*>(
      reinterpret_cast<uintptr_t>(g));
  auto lp = reinterpret_cast<__attribute__((address_space(3))) uint32_t*>(
      reinterpret_cast<uintptr_t>(l));
  __builtin_amdgcn_global_load_lds(gp, lp, 16, 0, 0);
}

// ---------------- prep: blocks [0,512) build W + c; blocks [512,1536) build A
__global__ __launch_bounds__(256) void prep_kernel(
    const float* __restrict__ x, const float* __restrict__ mu,
    const float* __restrict__ sg, unsigned short* __restrict__ A,
    unsigned short* __restrict__ W, float* __restrict__ c) {
  __shared__ float red[4];
  const int bid = blockIdx.x;
  const int t = threadIdx.x;
  if (bid < FF) {
    const int f = bid;
    float part = 0.f;
#pragma unroll
    for (int dd = 0; dd < 2; ++dd) {
      const int d = t + dd * 256;
      const float m = mu[f * DD + d];
      const float s = sg[f * DD + d];
      const float s2 = s * s;
      W[f * KDIM + d] = f2bf(s2);
      W[f * KDIM + DD + d] = f2bf(-2.f * s2 * m);
      part += s2 * m * m;
    }
#pragma unroll
    for (int off = 32; off > 0; off >>= 1) part += __shfl_down(part, off, 64);
    const int lane = t & 63, wave = t >> 6;
    if (lane == 0) red[wave] = part;
    __syncthreads();
    if (t == 0) c[f] = red[0] + red[1] + red[2] + red[3];
  } else {
    const int gid = (bid - FF) * 256 + t;     // 1024 blocks cover B*D/8
    const int i8 = gid * 8;
    const float4 v0 = *(const float4*)(x + i8);
    const float4 v1 = *(const float4*)(x + i8 + 4);
    const int b = i8 >> 9;
    const int d = i8 & 511;
    u16x8 q2, q1;
    q2[0] = f2bf(v0.x * v0.x); q2[1] = f2bf(v0.y * v0.y);
    q2[2] = f2bf(v0.z * v0.z); q2[3] = f2bf(v0.w * v0.w);
    q2[4] = f2bf(v1.x * v1.x); q2[5] = f2bf(v1.y * v1.y);
    q2[6] = f2bf(v1.z * v1.z); q2[7] = f2bf(v1.w * v1.w);
    q1[0] = f2bf(v0.x); q1[1] = f2bf(v0.y); q1[2] = f2bf(v0.z); q1[3] = f2bf(v0.w);
    q1[4] = f2bf(v1.x); q1[5] = f2bf(v1.y); q1[6] = f2bf(v1.z); q1[7] = f2bf(v1.w);
    *(u16x8*)(A + (size_t)b * KDIM + d) = q2;
    *(u16x8*)(A + (size_t)b * KDIM + DD + d) = q1;
  }
}

// ---------------- GEMM 64x64 tile, BK=64, 4 waves, dbuf single-barrier K-loop
// LDS column-XOR swizzle: 16B chunk at logical c16 of row r lives at phys
// c16 ^ (r&7). Staging picks the matching global addresses since
// global_load_lds forces LDS dest = base + lane*16.
__global__ __launch_bounds__(256) void gemm_kernel(
    const unsigned short* __restrict__ A, const unsigned short* __restrict__ W,
    const float* __restrict__ c, float* __restrict__ out) {
  __shared__ __align__(16) unsigned short As[2][64 * 64];
  __shared__ __align__(16) unsigned short Bs[2][64 * 64];
  const int m0 = blockIdx.y * 64;
  const int n0 = blockIdx.x * 64;
  const int tid = threadIdx.x;
  const int lane = tid & 63;
  const int wave = tid >> 6;

  f32x4 acc[2][2];
#pragma unroll
  for (int i = 0; i < 2; ++i)
#pragma unroll
    for (int j = 0; j < 2; ++j) acc[i][j] = (f32x4){0.f, 0.f, 0.f, 0.f};

  const int srow = lane >> 3;          // 0..7 within 8-row staging group
  const int sc16 = lane & 7;           // phys 16B chunk this lane lands in
  const int gcol = (sc16 ^ srow) * 8;  // logical column (elements) to fetch
  const int quad = lane >> 4;
  const int r = lane & 15;
  const int wm = (wave & 1) * 32;
  const int wn = (wave >> 1) * 32;

  // per-thread staging base pointers (row = base + srow; +8 rows for tI=1)
  const unsigned short* ag = A + (size_t)(m0 + wave * 16 + srow) * KDIM + gcol;
  const unsigned short* wg = W + (size_t)(n0 + wave * 16 + srow) * KDIM + gcol;
  const int rb = wave * 16;

  // prologue: stage k-slice 0 into buf 0
#pragma unroll
  for (int tI = 0; tI < 2; ++tI) {
    async16(ag + (size_t)tI * 8 * KDIM, &As[0][(rb + tI * 8) * 64]);
    async16(wg + (size_t)tI * 8 * KDIM, &Bs[0][(rb + tI * 8) * 64]);
  }

  for (int kt = 0; kt < KDIM / 64; ++kt) {
    const int cur = kt & 1;
    __syncthreads();  // drains vmcnt: buf[cur] staged; prev compute done with buf[cur^1]
    if (kt + 1 < KDIM / 64) {
      const int k1 = (kt + 1) * 64;
#pragma unroll
      for (int tI = 0; tI < 2; ++tI) {
        async16(ag + (size_t)tI * 8 * KDIM + k1, &As[cur ^ 1][(rb + tI * 8) * 64]);
        async16(wg + (size_t)tI * 8 * KDIM + k1, &Bs[cur ^ 1][(rb + tI * 8) * 64]);
      }
    }
#pragma unroll
    for (int kk = 0; kk < 2; ++kk) {
      const int lc = kk * 4 + quad;            // logical 16B chunk
      const int pc = (lc ^ (r & 7)) * 8;       // swizzled phys column
      bf16x8 a0 = *(const bf16x8*)&As[cur][(wm + r) * 64 + pc];
      bf16x8 a1 = *(const bf16x8*)&As[cur][(wm + 16 + r) * 64 + pc];
      bf16x8 b0 = *(const bf16x8*)&Bs[cur][(wn + r) * 64 + pc];
      bf16x8 b1 = *(const bf16x8*)&Bs[cur][(wn + 16 + r) * 64 + pc];
      acc[0][0] = __builtin_amdgcn_mfma_f32_16x16x32_bf16(a0, b0, acc[0][0], 0, 0, 0);
      acc[0][1] = __builtin_amdgcn_mfma_f32_16x16x32_bf16(a0, b1, acc[0][1], 0, 0, 0);
      acc[1][0] = __builtin_amdgcn_mfma_f32_16x16x32_bf16(a1, b0, acc[1][0], 0, 0, 0);
      acc[1][1] = __builtin_amdgcn_mfma_f32_16x16x32_bf16(a1, b1, acc[1][1], 0, 0, 0);
    }
  }

  // epilogue: D layout col=lane&15, row=(lane>>4)*4+reg
  const int col = lane & 15;
#pragma unroll
  for (int j = 0; j < 2; ++j) {
    const int f = n0 + wn + j * 16 + col;
    const float cf = c[f];
#pragma unroll
    for (int i = 0; i < 2; ++i) {
      const int mbase = m0 + wm + i * 16 + quad * 4;
#pragma unroll
      for (int rr = 0; rr < 4; ++rr) {
        const float d2 = acc[i][j][rr] + cf;
        const float loc = __expf(-sqrtf(fmaxf(d2, 0.f)));
        out[(size_t)(mbase + rr) * FF + f] = loc;
      }
    }
  }
}

// ---------------- softmax: 4 rows/block, one wave per row, in-place
__global__ __launch_bounds__(256) void softmax_kernel(
    float* __restrict__ out, const float* __restrict__ temp) {
  const int lane = threadIdx.x & 63;
  const int wave = threadIdx.x >> 6;
  const int row = blockIdx.x * 4 + wave;
  const float s = 1.f / (1.f + __expf(-temp[0]));
  float4* p = (float4*)(out + (size_t)row * FF + lane * 8);
  const float4 v0 = p[0];
  const float4 v1 = p[1];
  float l[8] = {v0.x * s, v0.y * s, v0.z * s, v0.w * s,
                v1.x * s, v1.y * s, v1.z * s, v1.w * s};
  float mx = l[0];
#pragma unroll
  for (int i = 1; i < 8; ++i) mx = fmaxf(mx, l[i]);
#pragma unroll
  for (int off = 32; off > 0; off >>= 1) mx = fmaxf(mx, __shfl_xor(mx, off, 64));
  float e[8], sum = 0.f;
#pragma unroll
  for (int i = 0; i < 8; ++i) { e[i] = __expf(l[i] - mx); sum += e[i]; }
#pragma unroll
  for (int off = 32; off > 0; off >>= 1) sum += __shfl_xor(sum, off, 64);
  const float inv = 1.f / sum;
  float4 w0 = {e[0] * inv, e[1] * inv, e[2] * inv, e[3] * inv};
  float4 w1 = {e[4] * inv, e[5] * inv, e[6] * inv, e[7] * inv};
  p[0] = w0; p[1] = w1;
}

// ---------------- fallback (no workspace): fp32 direct
__global__ __launch_bounds__(256) void naive_loc(
    const float* __restrict__ x, const float* __restrict__ mu,
    const float* __restrict__ sg, float* __restrict__ out) {
  __shared__ float xs[DD];
  const int b = blockIdx.x;
  for (int d = threadIdx.x; d < DD; d += 256) xs[d] = x[(size_t)b * DD + d];
  __syncthreads();
  for (int f = threadIdx.x; f < FF; f += 256) {
    float acc = 0.f;
    for (int d = 0; d < DD; ++d) {
      const float s = sg[(size_t)f * DD + d];
      const float df = (xs[d] - mu[(size_t)f * DD + d]) * s;
      acc = fmaf(df, df, acc);
    }
    out[(size_t)b * FF + f] = __expf(-sqrtf(acc));
  }
}

extern "C" void kernel_launch(void* const* d_in, const int* in_sizes, int n_in,
                              void* d_out, int out_size, void* d_ws, size_t ws_size,
                              hipStream_t stream) {
  const float* x = (const float*)d_in[0];
  const float* mu = (const float*)d_in[1];
  const float* sg = (const float*)d_in[2];
  const float* temp = (const float*)d_in[3];
  float* out = (float*)d_out;

  const size_t needA = (size_t)BB * KDIM * 2;          // 8 MB
  const size_t needW = (size_t)FF * KDIM * 2;          // 1 MB
  const size_t needC = (size_t)FF * 4;                 // 2 KB
  if (ws_size >= needA + needW + needC) {
    unsigned short* A = (unsigned short*)d_ws;
    unsigned short* W = A + (size_t)BB * KDIM;
    float* c = (float*)(W + (size_t)FF * KDIM);
    prep_kernel<<<FF + (BB * DD / 8) / 256, 256, 0, stream>>>(x, mu, sg, A, W, c);
    gemm_kernel<<<dim3(FF / 64, BB / 64), 256, 0, stream>>>(A, W, c, out);
  } else {
    naive_loc<<<BB, 256, 0, stream>>>(x, mu, sg, out);
  }
  softmax_kernel<<<BB / 4, 256, 0, stream>>>(out, temp);
}